// Round 5
// baseline (437.233 us; speedup 1.0000x reference)
//
#include <hip/hip_runtime.h>
#include <hip/hip_bf16.h>

#define T_ 256
#define B_ 16
#define S_ 64
#define D_ 256

typedef __attribute__((ext_vector_type(4))) int int4v;

__device__ __forceinline__ float tanh_fast(float x) {
    // tanh(x) = 1 - 2/(1+exp(2x)); saturates correctly at +-inf
    float e = __expf(2.0f * x);
    float r = __builtin_amdgcn_rcpf(e + 1.0f);
    return __builtin_fmaf(-2.0f, r, 1.0f);
}

// ---------------- W_x transpose: WxT[k][d] = W_x[d][k] ----------------
__global__ void k_transpose(const float* __restrict__ in, float* __restrict__ out) {
    __shared__ float tile[32][33];
    int tx = threadIdx.x & 31, ty = threadIdx.x >> 5;
    int bx = blockIdx.x & 7, by = blockIdx.x >> 3;
    tile[ty][tx] = in[(by * 32 + ty) * D_ + bx * 32 + tx];
    __syncthreads();
    out[(bx * 32 + ty) * D_ + by * 32 + tx] = tile[tx][ty];
}

// -------- Wxall[t*B+b][d] = bias[d] + sum_k x[t,b,k] * WxT[k][d] --------
__global__ __launch_bounds__(256) void k_wxall(const float* __restrict__ x,
                                               const float* __restrict__ WxT,
                                               const float* __restrict__ bias,
                                               float* __restrict__ wxall) {
    __shared__ float xs[16][D_];
    const int tid = threadIdx.x;
    const int row0 = blockIdx.x * 16;
    for (int r = 0; r < 16; ++r)
        xs[r][tid] = x[(size_t)(row0 + r) * D_ + tid];
    __syncthreads();
    float acc[16];
    float bv = bias[tid];
#pragma unroll
    for (int r = 0; r < 16; ++r) acc[r] = bv;
    for (int k = 0; k < D_; ++k) {
        float wv = WxT[k * D_ + tid];
#pragma unroll
        for (int r = 0; r < 16; ++r) acc[r] = __builtin_fmaf(wv, xs[r][k], acc[r]);
    }
    for (int r = 0; r < 16; ++r)
        wxall[(size_t)(row0 + r) * D_ + tid] = acc[r];
}

// ---------------- main recurrence (i8 MFMA K=64, 16 waves/block) ----------------
// grid = 256 blocks: block -> (b = blk>>4, slots s0..s0+3, s0 = (blk&15)*4)
// block = 1024 threads = 16 waves (4/SIMD); wave w owns n-slice [16w, 16w+16)
// A rows m hold slot m&3  ->  C row m = quad*4+reg holds slot reg (all quads):
// thread finalizes slot = quad, col d = 16w + l16, value acc[quad]. 1 tanh/thread.
__global__ __launch_bounds__(1024, 4) void k_rec(
    const float* __restrict__ Wh,      // [D][D] (n-major: Wh[n][k])
    const float* __restrict__ wxall,   // [T*B][D], bias folded in
    const float* __restrict__ z,       // [T*B][D]
    const float* __restrict__ h0,      // [B][S][D]
    const float* __restrict__ Cvec,    // [S]
    float* __restrict__ outputs,       // [T*B][D], pre-zeroed (atomic accum)
    float* __restrict__ h_out)         // [(T+1)*B][S][D]
{
    const int tid  = threadIdx.x;
    const int w    = tid >> 6;
    const int lane = tid & 63;
    const int l16  = lane & 15;
    const int quad = lane >> 4;
    const int b    = blockIdx.x >> 4;
    const int s0   = (blockIdx.x & 15) * 4;
    const int d    = (w << 4) | l16;     // this thread's output column
    const int slot = quad;               // this thread's slot

    // ping-pong h buffer, i8. Row stride 288 B: the 16 distinct b128 A-chunks
    // (4 rows x 4 quads) cover each bank range exactly 2-way = free (m136).
    __shared__ __align__(16) signed char hA8[2][4][288];

    // init hA8[0] from h0 and write h[0] = h0  (1024 threads = exactly 4*256)
    {
        int r = tid >> 8, dd = tid & 255;
        float v = h0[(size_t)(b * S_ + s0 + r) * D_ + dd];
        float vc = fminf(fmaxf(v, -1.0f), 1.0f);
        hA8[0][r][dd] = (signed char)__float2int_rn(vc * 127.0f);
        h_out[(size_t)(b * S_ + s0 + r) * D_ + dd] = v;
    }

    // ---- pass 1: per-column absmax of Wh for this lane's column n = 16w+l16 ----
    // lane scans k = kt*64 + quad*16 + {0..15}; quads jointly cover all 256 k
    // -> shfl_xor max over lane bits 4,5 gives the full-column max on all quads.
    const float* wr = Wh + (size_t)d * D_ + quad * 16;
    float cm = 1e-20f;
#pragma unroll
    for (int kt = 0; kt < 4; ++kt) {
        const float* p = wr + kt * 64;
#pragma unroll
        for (int j = 0; j < 16; j += 4) {
            float4 v = *(const float4*)(p + j);
            cm = fmaxf(cm, fmaxf(fmaxf(fabsf(v.x), fabsf(v.y)),
                                 fmaxf(fabsf(v.z), fabsf(v.w))));
        }
    }
    cm = fmaxf(cm, __shfl_xor(cm, 16, 64));
    cm = fmaxf(cm, __shfl_xor(cm, 32, 64));

    // ---- pass 2: quantize Wh -> i8 B-fragments (16 VGPRs) ----
    // lane holds B[k = kt*64 + quad*16 + j][n = 16w + l16]
    int4v Bf[4];
    {
        const float rs = 127.0f / cm;
#pragma unroll
        for (int kt = 0; kt < 4; ++kt) {
            const float* p = wr + kt * 64;
            int4v frag;
#pragma unroll
            for (int r = 0; r < 4; ++r) {
                float4 v = *(const float4*)(p + r * 4);
                int q0 = __float2int_rn(v.x * rs) & 255;
                int q1 = __float2int_rn(v.y * rs) & 255;
                int q2 = __float2int_rn(v.z * rs) & 255;
                int q3 = __float2int_rn(v.w * rs) & 255;
                frag[r] = q0 | (q1 << 8) | (q2 << 16) | (q3 << 24);
            }
            Bf[kt] = frag;
        }
    }
    const float dscale = cm * (1.0f / 16129.0f);   // cm / 127^2
    const float cq = Cvec[s0 + slot];
    __syncthreads();

    float wx = wxall[(unsigned)b * D_ + d];   // t=0 row
    float zv = z[(unsigned)b * D_ + d];

    // running output offsets
    unsigned hb = (unsigned)(1 * B_ + b) * (S_ * D_) + (unsigned)(s0 + slot) * D_ + d;
    unsigned ob = (unsigned)b * D_ + d;

    // 2-deep deferred global stores (parity = t&1), flushed at t+2 so the
    // pre-barrier vmcnt drain never waits on a fresh HBM store/atomic.
    float dh_0, dos_0; unsigned dhb_0, dob_0;
    float dh_1, dos_1; unsigned dhb_1, dob_1;

#define STEP(t, CUR, NXT)                                                      \
    {                                                                          \
        const signed char* ap = &hA8[CUR][l16 & 3][quad * 16];                 \
        int4v Af0 = *(const int4v*)(ap);                                       \
        int4v Af1 = *(const int4v*)(ap + 64);                                  \
        int4v Af2 = *(const int4v*)(ap + 128);                                 \
        int4v Af3 = *(const int4v*)(ap + 192);                                 \
        if ((t) >= 2) { /* flush step t-2 (same parity) */                     \
            __builtin_nontemporal_store(dh_##CUR, h_out + dhb_##CUR);          \
            if (lane < 16) atomicAdd(outputs + dob_##CUR, dos_##CUR);          \
        }                                                                      \
        const int tn = ((t) + 1 < T_) ? (t) + 1 : (t);                         \
        float wx_n = wxall[(unsigned)(tn * B_ + b) * D_ + d];                  \
        float zv_n = z[(unsigned)(tn * B_ + b) * D_ + d];                      \
        int4v acc = {0, 0, 0, 0};                                              \
        acc = __builtin_amdgcn_mfma_i32_16x16x64_i8(Af0, Bf[0], acc, 0, 0, 0); \
        acc = __builtin_amdgcn_mfma_i32_16x16x64_i8(Af1, Bf[1], acc, 0, 0, 0); \
        acc = __builtin_amdgcn_mfma_i32_16x16x64_i8(Af2, Bf[2], acc, 0, 0, 0); \
        acc = __builtin_amdgcn_mfma_i32_16x16x64_i8(Af3, Bf[3], acc, 0, 0, 0); \
        /* slot = reg index (A row m holds slot m&3): pick acc[quad] */        \
        int va = (quad & 1) ? acc[1] : acc[0];                                 \
        int vb = (quad & 1) ? acc[3] : acc[2];                                 \
        int vi = (quad & 2) ? vb : va;                                         \
        float hv = tanh_fast(__builtin_fmaf((float)vi, dscale, wx));           \
        hA8[NXT][slot][d] = (signed char)__float2int_rn(hv * 127.0f);          \
        float sig  = __builtin_amdgcn_rcpf(1.0f + __expf(-zv));                \
        float part = cq * hv;                                                  \
        part += __shfl_xor(part, 16, 64);                                      \
        part += __shfl_xor(part, 32, 64);  /* sum over 4 slots for col d */    \
        dh_##CUR  = hv;                                                        \
        dhb_##CUR = hb; hb += (unsigned)(B_ * S_ * D_);                        \
        dob_##CUR = ob; ob += (unsigned)(B_ * D_);                             \
        dos_##CUR = part * (zv * sig);                                         \
        wx = wx_n; zv = zv_n;                                                  \
        __syncthreads();                                                       \
    }

    for (int t2 = 0; t2 < T_; t2 += 2) {
        STEP(t2, 0, 1)
        STEP(t2 + 1, 1, 0)
    }
#undef STEP

    // tail: flush the last two steps
    __builtin_nontemporal_store(dh_0, h_out + dhb_0);
    if (lane < 16) atomicAdd(outputs + dob_0, dos_0);
    __builtin_nontemporal_store(dh_1, h_out + dhb_1);
    if (lane < 16) atomicAdd(outputs + dob_1, dos_1);
}

extern "C" void kernel_launch(void* const* d_in, const int* in_sizes, int n_in,
                              void* d_out, int out_size, void* d_ws, size_t ws_size,
                              hipStream_t stream) {
    const float* x    = (const float*)d_in[0];
    const float* z    = (const float*)d_in[1];
    const float* h0   = (const float*)d_in[2];
    const float* W_x  = (const float*)d_in[3];
    const float* W_h  = (const float*)d_in[4];
    const float* bias = (const float*)d_in[5];
    const float* C    = (const float*)d_in[6];

    float* outputs = (float*)d_out;                     // [T*B*D]
    float* h_out   = outputs + (size_t)T_ * B_ * D_;    // [(T+1)*B*S*D]

    float* WxT   = (float*)d_ws;                        // D*D floats
    float* wxall = WxT + D_ * D_;                       // T*B*D floats

    hipMemsetAsync(outputs, 0, (size_t)T_ * B_ * D_ * sizeof(float), stream);
    k_transpose<<<64, 1024, 0, stream>>>(W_x, WxT);
    k_wxall<<<T_ * B_ / 16, 256, 0, stream>>>(x, WxT, bias, wxall);
    k_rec<<<B_ * S_ / 4, 1024, 0, stream>>>(W_h, wxall, z, h0, C, outputs, h_out);
}